// Round 5
// baseline (4094.219 us; speedup 1.0000x reference)
//
#include <hip/hip_runtime.h>

// SpikeMLP — R16: register-pressure fix + LDS double-buffer.
// Chain contract (FROZEN, R14/R15 absmax=0.0): per C element
//   pacc = fma(a_k, w_k, pacc), k = 0..1023 strictly ascending, single
//   accumulator, fp32, contract off; recurrence fp32 ufunc order.
//   MFMA / k-reassociation forbidden.
// R15 post-mortem: VGPR_Count=68 for an 8x8 tile (needs ~90+ live) =>
//   compiler spilled accumulators to AGPRs (accvgpr round-trips) --
//   ~35% of VALU issue was shuffle, FMA stuck at ~51% of fp32 peak.
// R16 (mapping only, arithmetic identical):
//   - __launch_bounds__(256, 2): VGPR cap 256 -> 64 acc + operands all in
//     arch VGPRs, no AGPR traffic. 2 blocks/CU.
//   - LDS double-buffer (2x32KB = 64KB, exactly 2 blocks/CU): global loads
//     for kt+1 issued before the 4096-cycle FMA block; stage-writes go to
//     the idle buffer; ONE barrier per ktile (was 2 + vmcnt drain).
// Predicted: VGPR ~120-160, Occ ~25%, VALUBusy ~88% FMA-dominant,
//   big GEMM ~1050-1250 us, total ~2.9-3.1 ms, absmax 0.0.

typedef __bf16 bf16x8_t __attribute__((ext_vector_type(8)));

static constexpr int BSZ   = 4096;
static constexpr int D_IN  = 1024;
static constexpr int H1    = 1024;
static constexpr int D_OUT = 512;
static constexpr int M_ROWS = BSZ * 16;   // 65536, m = b*16 + t

// ---------------------------------------------------------------------------
// pack X [B, D_in, T=16] f32 -> A [m = b*16 + t][d] bf16 (spikes exactly 0/1)
// ---------------------------------------------------------------------------
__global__ void pack_x(const float* __restrict__ X, __bf16* __restrict__ A) {
    const int P = blockIdx.x * 256 + threadIdx.x;     // P = b*1024 + d
    const int b = P >> 10, d = P & 1023;
    const float4* xp = (const float4*)(X + (size_t)P * 16);
    float4 x0 = xp[0], x1 = xp[1], x2 = xp[2], x3 = xp[3];
    const float v[16] = {x0.x, x0.y, x0.z, x0.w, x1.x, x1.y, x1.z, x1.w,
                         x2.x, x2.y, x2.z, x2.w, x3.x, x3.y, x3.z, x3.w};
#pragma unroll
    for (int t = 0; t < 16; ++t)
        A[((size_t)(b * 16 + t)) * 1024 + d] = (__bf16)v[t];
}

// ---------------------------------------------------------------------------
// GEMM, reference fp32 chain. C[m][n] = A[m,:] . W[n,:], K = 1024.
// Block 128(M) x 128(N), 256 threads, 8x8 per thread. BK = 32, k-major LDS,
// double-buffered. Single ascending accumulator over full K (frozen).
// Thread (tx,ty): rows ty*8..+7, cols {tx*4..+3, 64+tx*4..+3}.
// ---------------------------------------------------------------------------
__global__ __launch_bounds__(256, 2) void gemm_np(
    const __bf16* __restrict__ A,   // [M, 1024] spikes (values exactly 0/1)
    const float* __restrict__ W,    // [N, 1024] fp32 weights (raw input)
    float* __restrict__ C,          // [M, N] fp32
    int N) {
#pragma clang fp contract(off)
    __shared__ float As[2][32][128];   // [buf][kk][m]  2 x 16 KB
    __shared__ float Ws[2][32][128];   // [buf][kk][n]  2 x 16 KB

    const int tid = threadIdx.x;
    const int tx = tid & 15;        // n quads: tx*4 and 64+tx*4
    const int ty = tid >> 4;        // m group: rows ty*8 .. ty*8+7
    const int m0 = blockIdx.x * 128, n0 = blockIdx.y * 128;

    const int arow = tid & 127, akh = tid >> 7;   // staging: row, k-half

    const __bf16* Ab = A + (size_t)(m0 + arow) * 1024 + akh * 16;
    const float*  Wb = W + (size_t)(n0 + arow) * 1024 + akh * 16;

    float pacc[8][8] = {};   // single-chain accumulators

    // prologue: stage tile 0 into buffer 0
    {
        bf16x8_t av0 = *(const bf16x8_t*)(Ab);
        bf16x8_t av1 = *(const bf16x8_t*)(Ab + 8);
        float4   wv0 = *(const float4*)(Wb);
        float4   wv1 = *(const float4*)(Wb + 4);
        float4   wv2 = *(const float4*)(Wb + 8);
        float4   wv3 = *(const float4*)(Wb + 12);
#pragma unroll
        for (int e = 0; e < 8; ++e) {
            As[0][akh * 16 + e][arow]     = (float)av0[e];
            As[0][akh * 16 + 8 + e][arow] = (float)av1[e];
        }
        Ws[0][akh * 16 +  0][arow] = wv0.x;
        Ws[0][akh * 16 +  1][arow] = wv0.y;
        Ws[0][akh * 16 +  2][arow] = wv0.z;
        Ws[0][akh * 16 +  3][arow] = wv0.w;
        Ws[0][akh * 16 +  4][arow] = wv1.x;
        Ws[0][akh * 16 +  5][arow] = wv1.y;
        Ws[0][akh * 16 +  6][arow] = wv1.z;
        Ws[0][akh * 16 +  7][arow] = wv1.w;
        Ws[0][akh * 16 +  8][arow] = wv2.x;
        Ws[0][akh * 16 +  9][arow] = wv2.y;
        Ws[0][akh * 16 + 10][arow] = wv2.z;
        Ws[0][akh * 16 + 11][arow] = wv2.w;
        Ws[0][akh * 16 + 12][arow] = wv3.x;
        Ws[0][akh * 16 + 13][arow] = wv3.y;
        Ws[0][akh * 16 + 14][arow] = wv3.z;
        Ws[0][akh * 16 + 15][arow] = wv3.w;
    }
    __syncthreads();

    int cur = 0;
    for (int kt = 0; kt < 32; ++kt) {
        // issue next-tile global loads (hidden under the FMA block)
        const int ktn = (kt < 31) ? kt + 1 : 31;   // clamped redundant last
        const int k0n = ktn * 32;
        bf16x8_t av0 = *(const bf16x8_t*)(Ab + k0n);
        bf16x8_t av1 = *(const bf16x8_t*)(Ab + k0n + 8);
        float4   wv0 = *(const float4*)(Wb + k0n);
        float4   wv1 = *(const float4*)(Wb + k0n + 4);
        float4   wv2 = *(const float4*)(Wb + k0n + 8);
        float4   wv3 = *(const float4*)(Wb + k0n + 12);

        // compute current buffer (strictly k-ascending, frozen chain)
#pragma unroll
        for (int kk = 0; kk < 32; ++kk) {
            float4 a0 = *(const float4*)&As[cur][kk][ty * 8];
            float4 a1 = *(const float4*)&As[cur][kk][ty * 8 + 4];
            float4 w0 = *(const float4*)&Ws[cur][kk][tx * 4];
            float4 w1 = *(const float4*)&Ws[cur][kk][64 + tx * 4];
            const float a[8] = {a0.x, a0.y, a0.z, a0.w, a1.x, a1.y, a1.z, a1.w};
            const float w[8] = {w0.x, w0.y, w0.z, w0.w, w1.x, w1.y, w1.z, w1.w};
#pragma unroll
            for (int i = 0; i < 8; ++i)
#pragma unroll
                for (int j = 0; j < 8; ++j)
                    pacc[i][j] = __builtin_fmaf(a[i], w[j], pacc[i][j]);
        }

        // stage next tile into the idle buffer (no reader conflicts)
        const int nxt = cur ^ 1;
#pragma unroll
        for (int e = 0; e < 8; ++e) {
            As[nxt][akh * 16 + e][arow]     = (float)av0[e];
            As[nxt][akh * 16 + 8 + e][arow] = (float)av1[e];
        }
        Ws[nxt][akh * 16 +  0][arow] = wv0.x;
        Ws[nxt][akh * 16 +  1][arow] = wv0.y;
        Ws[nxt][akh * 16 +  2][arow] = wv0.z;
        Ws[nxt][akh * 16 +  3][arow] = wv0.w;
        Ws[nxt][akh * 16 +  4][arow] = wv1.x;
        Ws[nxt][akh * 16 +  5][arow] = wv1.y;
        Ws[nxt][akh * 16 +  6][arow] = wv1.z;
        Ws[nxt][akh * 16 +  7][arow] = wv1.w;
        Ws[nxt][akh * 16 +  8][arow] = wv2.x;
        Ws[nxt][akh * 16 +  9][arow] = wv2.y;
        Ws[nxt][akh * 16 + 10][arow] = wv2.z;
        Ws[nxt][akh * 16 + 11][arow] = wv2.w;
        Ws[nxt][akh * 16 + 12][arow] = wv3.x;
        Ws[nxt][akh * 16 + 13][arow] = wv3.y;
        Ws[nxt][akh * 16 + 14][arow] = wv3.z;
        Ws[nxt][akh * 16 + 15][arow] = wv3.w;
        __syncthreads();   // writes visible; readers of old buf done
        cur = nxt;
    }

#pragma unroll
    for (int i = 0; i < 8; ++i) {
        float4 s0 = {pacc[i][0], pacc[i][1], pacc[i][2], pacc[i][3]};
        float4 s1 = {pacc[i][4], pacc[i][5], pacc[i][6], pacc[i][7]};
        const size_t r = (size_t)(m0 + ty * 8 + i) * N;
        *(float4*)&C[r + n0 + tx * 4]      = s0;
        *(float4*)&C[r + n0 + 64 + tx * 4] = s1;
    }
}

// ---------------------------------------------------------------------------
// fp32 LIF recurrence, numpy ufunc order, contraction off (frozen).
// ---------------------------------------------------------------------------
__global__ void recur_hidden(const float* __restrict__ Z, const float* __restrict__ bias,
                             __bf16* __restrict__ S) {
#pragma clang fp contract(off)
    const int idx = blockIdx.x * 256 + threadIdx.x;   // b*1024 + n
    const int n = idx & 1023, b = idx >> 10;
    const float bb = bias[n];
    float c = 0.f, v = 0.f, s = 0.f;
#pragma unroll
    for (int t = 0; t < 16; ++t) {
        const float z = Z[(size_t)(b * 16 + t) * 1024 + n];
        const float t1 = c * 0.5f;
        const float t2 = t1 + z;
        c = t2 + bb;
        const float u1 = v * 0.75f;
        const float u2 = u1 * (1.0f - s);
        v = u2 + c;
        s = (v > 0.5f) ? 1.0f : 0.0f;
        S[(size_t)(b * 16 + t) * 1024 + n] = (__bf16)s;   // exact 0/1
    }
}

__global__ void recur_out(const float* __restrict__ Z, const float* __restrict__ bias,
                          float* __restrict__ Out) {
#pragma clang fp contract(off)
    const int idx = blockIdx.x * 256 + threadIdx.x;   // b*512 + n
    const int n = idx & 511, b = idx >> 9;
    const float bb = bias[n];
    float c = 0.f, v = 0.f, s = 0.f, acm = 0.f;
#pragma unroll
    for (int t = 0; t < 16; ++t) {
        const float z = Z[(size_t)(b * 16 + t) * 512 + n];
        const float t1 = c * 0.5f;
        const float t2 = t1 + z;
        c = t2 + bb;
        const float u1 = v * 0.75f;
        const float u2 = u1 * (1.0f - s);
        v = u2 + c;
        s = (v > 0.5f) ? 1.0f : 0.0f;
        acm += s;                                     // small ints, exact
    }
    Out[(size_t)b * 512 + n] = acm * 0.0625f;         // exact (2^-4)
}

// ---------------------------------------------------------------------------
extern "C" void kernel_launch(void* const* d_in, const int* in_sizes, int n_in,
                              void* d_out, int out_size, void* d_ws, size_t ws_size,
                              hipStream_t stream) {
    const float* X  = (const float*)d_in[0];
    const float* W1 = (const float*)d_in[1];
    const float* b1 = (const float*)d_in[2];
    const float* W2 = (const float*)d_in[3];
    const float* b2 = (const float*)d_in[4];
    const float* Wo = (const float*)d_in[5];
    const float* bo = (const float*)d_in[6];

    char* ws = (char*)d_ws;
    __bf16* A1 = (__bf16*)ws;                      // 128 MiB (reused as S2)
    __bf16* S1 = (__bf16*)(ws + (128ull << 20));   // 128 MiB
    float*  Z  = (float*)(ws + (256ull << 20));    // 256 MiB ([M, 1024] f32)
    __bf16* S2 = A1;

    pack_x<<<(BSZ * D_IN) / 256, 256, 0, stream>>>(X, A1);

    // layer 1
    gemm_np<<<dim3(M_ROWS / 128, H1 / 128), 256, 0, stream>>>(A1, W1, Z, H1);
    recur_hidden<<<(BSZ * H1) / 256, 256, 0, stream>>>(Z, b1, S1);
    // layer 2
    gemm_np<<<dim3(M_ROWS / 128, H1 / 128), 256, 0, stream>>>(S1, W2, Z, H1);
    recur_hidden<<<(BSZ * H1) / 256, 256, 0, stream>>>(Z, b2, S2);
    // output layer
    gemm_np<<<dim3(M_ROWS / 128, D_OUT / 128), 256, 0, stream>>>(S2, Wo, Z, D_OUT);
    recur_out<<<(BSZ * D_OUT) / 256, 256, 0, stream>>>(Z, bo, (float*)d_out);
}